// Round 8
// baseline (319.314 us; speedup 1.0000x reference)
//
#include <hip/hip_runtime.h>
#include <hip/hip_bf16.h>

typedef __hip_bfloat16 bf16;
typedef __attribute__((ext_vector_type(8))) short bf16x8;
typedef __attribute__((ext_vector_type(4))) float f32x4;

constexpr int NB  = 4;
constexpr int NH  = 12;
constexpr int SEQ = 1024;
constexpr int HD  = 64;
constexpr int DM  = 768;
constexpr int LDA = 40;   // padded LDS row (elems)

__device__ __forceinline__ bf16x8 ld8(const bf16* p){ return *(const bf16x8*)p; }
__device__ __forceinline__ f32x4 mfma16(bf16x8 a, bf16x8 b, f32x4 c){
  return __builtin_amdgcn_mfma_f32_16x16x32_bf16(a, b, c, 0, 0, 0);
}
union U8 { bf16x8 v; bf16 h[8]; };

// ---------------- wprep: LDS-tiled transpose, fp32 W[.][d][e] -> bf16 WT[.][e][d] ----------------
__global__ __launch_bounds__(256) void wprep(const float* __restrict__ Wq, const float* __restrict__ Wk,
                      const float* __restrict__ Wv, const float* __restrict__ Wo,
                      bf16* __restrict__ WqTh, bf16* __restrict__ WqTl,
                      bf16* __restrict__ WkTh, bf16* __restrict__ WkTl,
                      bf16* __restrict__ WvT,  bf16* __restrict__ WoT){
  __shared__ float sT[64][65];
  const int tid = threadIdx.x;
  const int dt = blockIdx.x, y = blockIdx.y;
  const float* src; bf16* dh; bf16* dl = nullptr;
  if (y < 36){
    int z = y / 12, h = y % 12;
    src = (z==0 ? Wq : z==1 ? Wk : Wv) + (size_t)h*DM*HD;
    dh  = (z==0 ? WqTh : z==1 ? WkTh : WvT) + (size_t)h*HD*DM;
    if (z==0) dl = WqTl + (size_t)h*HD*DM;
    if (z==1) dl = WkTl + (size_t)h*HD*DM;
  } else { src = Wo; dh = WoT; }

  {
    int r = tid >> 2, c = (tid & 3) * 16;
    const float* sp = src + ((size_t)(dt*64 + r))*HD + c;
    f32x4 v0 = *(const f32x4*)sp, v1 = *(const f32x4*)(sp+4),
          v2 = *(const f32x4*)(sp+8), v3 = *(const f32x4*)(sp+12);
    #pragma unroll
    for (int j = 0; j < 4; j++){
      sT[r][c+j] = v0[j]; sT[r][c+4+j] = v1[j]; sT[r][c+8+j] = v2[j]; sT[r][c+12+j] = v3[j];
    }
  }
  __syncthreads();
  {
    int e = tid >> 2, co = (tid & 3) * 16;
    U8 uh0, ul0, uh1, ul1;
    #pragma unroll
    for (int j = 0; j < 8; j++){
      float v = sT[co + j][e];
      bf16 hi = __float2bfloat16(v);
      uh0.h[j] = hi; ul0.h[j] = __float2bfloat16(v - __bfloat162float(hi));
    }
    #pragma unroll
    for (int j = 0; j < 8; j++){
      float v = sT[co + 8 + j][e];
      bf16 hi = __float2bfloat16(v);
      uh1.h[j] = hi; ul1.h[j] = __float2bfloat16(v - __bfloat162float(hi));
    }
    size_t o = (size_t)e*DM + dt*64 + co;
    *(bf16x8*)(dh + o) = uh0.v; *(bf16x8*)(dh + o + 8) = uh1.v;
    if (dl){ *(bf16x8*)(dl + o) = ul0.v; *(bf16x8*)(dl + o + 8) = ul1.v; }
  }
}

// ---------------- xprep ----------------
__global__ __launch_bounds__(256) void xprep(const float* __restrict__ x,
                                             bf16* __restrict__ xh, bf16* __restrict__ xl){
  size_t base = ((size_t)blockIdx.x*256 + threadIdx.x)*8;
  f32x4 a = *(const f32x4*)(x + base), b = *(const f32x4*)(x + base + 4);
  U8 uh, ul;
  #pragma unroll
  for (int j = 0; j < 4; j++){
    bf16 h0 = __float2bfloat16(a[j]);
    uh.h[j] = h0; ul.h[j] = __float2bfloat16(a[j] - __bfloat162float(h0));
    bf16 h1 = __float2bfloat16(b[j]);
    uh.h[4+j] = h1; ul.h[4+j] = __float2bfloat16(b[j] - __bfloat162float(h1));
  }
  *(bf16x8*)(xh + base) = uh.v;
  *(bf16x8*)(xl + base) = ul.v;
}

// ---------------- kproj: LDS-staged GEMM, Q+K+V in ONE pass ----------------
// Q,K: hi/lo 3-term into [nh][t][e]; V: 1-term into Vt [nh][e][t].
// x tiles staged once and shared by all three projections.
__global__ __launch_bounds__(256) void kproj(const bf16* __restrict__ xh, const bf16* __restrict__ xl,
    const bf16* __restrict__ WqTh, const bf16* __restrict__ WqTl,
    const bf16* __restrict__ WkTh, const bf16* __restrict__ WkTl,
    const bf16* __restrict__ WvT,
    bf16* __restrict__ Qhi, bf16* __restrict__ Qlo,
    bf16* __restrict__ Khi, bf16* __restrict__ Klo, bf16* __restrict__ Vt){
  __shared__ bf16 sA[2][128*LDA];
  __shared__ bf16 sB[5][64*LDA];
  const int tid = threadIdx.x;
  const int lane = tid & 63, w = tid >> 6;
  const int quad = lane >> 4, lc = lane & 15;
  const int mb = blockIdx.x, h = blockIdx.y;
  const int sr = tid >> 2;
  const int sc = (tid & 3) * 8;
  const int wm = w & 1, wn = w >> 1;

  const bf16* Bqh = WqTh + (size_t)h*HD*DM;
  const bf16* Bql = WqTl + (size_t)h*HD*DM;
  const bf16* Bkh = WkTh + (size_t)h*HD*DM;
  const bf16* Bkl = WkTl + (size_t)h*HD*DM;
  const bf16* Av  = WvT  + (size_t)h*HD*DM;
  f32x4 aq[4][2] = {}, ak[4][2] = {}, av[2][4] = {};
  bf16x8 pa0,pa1,pa2,pa3,pq0,pq1,pk0,pk1,pv0;
  auto ldchunk = [&](int kc){
    size_t col = (size_t)kc*32 + sc;
    pa0 = ld8(xh + (size_t)(mb*128 + sr)*DM + col);
    pa1 = ld8(xh + (size_t)(mb*128 + sr + 64)*DM + col);
    pa2 = ld8(xl + (size_t)(mb*128 + sr)*DM + col);
    pa3 = ld8(xl + (size_t)(mb*128 + sr + 64)*DM + col);
    pq0 = ld8(Bqh + (size_t)sr*DM + col);
    pq1 = ld8(Bql + (size_t)sr*DM + col);
    pk0 = ld8(Bkh + (size_t)sr*DM + col);
    pk1 = ld8(Bkl + (size_t)sr*DM + col);
    pv0 = ld8(Av  + (size_t)sr*DM + col);
  };
  ldchunk(0);
  for (int kc = 0; kc < DM/32; kc++){
    *(bf16x8*)&sA[0][sr*LDA + sc] = pa0;
    *(bf16x8*)&sA[0][(sr+64)*LDA + sc] = pa1;
    *(bf16x8*)&sA[1][sr*LDA + sc] = pa2;
    *(bf16x8*)&sA[1][(sr+64)*LDA + sc] = pa3;
    *(bf16x8*)&sB[0][sr*LDA + sc] = pq0;
    *(bf16x8*)&sB[1][sr*LDA + sc] = pq1;
    *(bf16x8*)&sB[2][sr*LDA + sc] = pk0;
    *(bf16x8*)&sB[3][sr*LDA + sc] = pk1;
    *(bf16x8*)&sB[4][sr*LDA + sc] = pv0;
    __syncthreads();
    if (kc < DM/32 - 1) ldchunk(kc + 1);
    bf16x8 bqh[2], bql[2], bkh[2], bkl[2];
    #pragma unroll
    for (int nt = 0; nt < 2; nt++){
      int ro = (wn*32 + nt*16 + lc)*LDA + quad*8;
      bqh[nt] = *(const bf16x8*)&sB[0][ro];
      bql[nt] = *(const bf16x8*)&sB[1][ro];
      bkh[nt] = *(const bf16x8*)&sB[2][ro];
      bkl[nt] = *(const bf16x8*)&sB[3][ro];
    }
    #pragma unroll
    for (int mt = 0; mt < 4; mt++){
      bf16x8 ah = *(const bf16x8*)&sA[0][(wm*64 + mt*16 + lc)*LDA + quad*8];
      bf16x8 al = *(const bf16x8*)&sA[1][(wm*64 + mt*16 + lc)*LDA + quad*8];
      #pragma unroll
      for (int nt = 0; nt < 2; nt++){
        aq[mt][nt] = mfma16(ah, bqh[nt], aq[mt][nt]);
        aq[mt][nt] = mfma16(ah, bql[nt], aq[mt][nt]);
        aq[mt][nt] = mfma16(al, bqh[nt], aq[mt][nt]);
        ak[mt][nt] = mfma16(ah, bkh[nt], ak[mt][nt]);
        ak[mt][nt] = mfma16(ah, bkl[nt], ak[mt][nt]);
        ak[mt][nt] = mfma16(al, bkh[nt], ak[mt][nt]);
      }
    }
    // V projection reuses the staged xh tiles as the B operand (z=1's exact pattern)
    {
      bf16x8 btv[4];
      #pragma unroll
      for (int nt = 0; nt < 4; nt++)
        btv[nt] = *(const bf16x8*)&sA[0][(wn*64 + nt*16 + lc)*LDA + quad*8];
      #pragma unroll
      for (int mt = 0; mt < 2; mt++){
        bf16x8 a = *(const bf16x8*)&sB[4][(wm*32 + mt*16 + lc)*LDA + quad*8];
        #pragma unroll
        for (int nt = 0; nt < 4; nt++)
          av[mt][nt] = mfma16(a, btv[nt], av[mt][nt]);
      }
    }
    __syncthreads();
  }
  // Q/K epilogue
  #pragma unroll
  for (int mt = 0; mt < 4; mt++){
    #pragma unroll
    for (int nt = 0; nt < 2; nt++){
      #pragma unroll
      for (int i = 0; i < 4; i++){
        int tg = mb*128 + wm*64 + mt*16 + quad*4 + i;
        int e  = wn*32 + nt*16 + lc;
        int n = tg >> 10, t = tg & 1023;
        size_t o = ((size_t)(n*NH + h)*SEQ + t)*HD + e;
        float vq = aq[mt][nt][i];
        bf16 hq = __float2bfloat16(vq);
        Qhi[o] = hq;
        Qlo[o] = __float2bfloat16(vq - __bfloat162float(hq));
        float vk = ak[mt][nt][i];
        bf16 hk = __float2bfloat16(vk);
        Khi[o] = hk;
        Klo[o] = __float2bfloat16(vk - __bfloat162float(hk));
      }
    }
  }
  // V epilogue
  #pragma unroll
  for (int mt = 0; mt < 2; mt++){
    #pragma unroll
    for (int nt = 0; nt < 4; nt++){
      #pragma unroll
      for (int i = 0; i < 4; i++){
        int e  = wm*32 + mt*16 + quad*4 + i;
        int tg = mb*128 + wn*64 + nt*16 + lc;
        int n = tg >> 10, t = tg & 1023;
        Vt[((size_t)(n*NH + h)*HD + e)*SEQ + t] = __float2bfloat16(av[mt][nt][i]);
      }
    }
  }
}

// ---------------- fused scores + softmax + attn-stream + PV ----------------
// 32 Q-rows per block (2 row-tiles); P processed in two 512-col halves.
// Grid 1536 = 8 XCD x 6 heads x 32 tt-pairs, LPT descending.
__global__ __launch_bounds__(256, 2) void kattn_pv(const bf16* __restrict__ Qhi, const bf16* __restrict__ Qlo,
                                                   const bf16* __restrict__ Khi, const bf16* __restrict__ Klo,
                                                   const bf16* __restrict__ Vt,
                                                   float* __restrict__ attn, bf16* __restrict__ O){
  __shared__ bf16 sP[32][528];
  __shared__ float msh[4][32], lsh[4][32];
  const int tid = threadIdx.x;
  const int lane = tid & 63, w = tid >> 6;
  const int quad = lane >> 4, lc = lane & 15;
  const int lin = blockIdx.x;          // 0..1535
  const int xcd = lin & 7;
  const int c   = lin >> 3;            // 0..191
  const int nh  = xcd * 6 + (c >> 5);  // 48 heads / 8 XCDs
  const int tp  = 31 - (c & 31);       // tt-pair, DESCENDING -> LPT
  const int t0  = tp * 32;
  const size_t base = (size_t)nh * SEQ * HD;
  const float NEGINF = -__builtin_inff();

  const int kend = t0 + 32;            // multiple of 32 -> no PV tail fill
  const int T_act = 2*tp + 2;          // active 16-wide col-tiles
  const int cnt   = (T_act + 3) >> 2;
  const int wbase = w * cnt;
  int wtiles = T_act - wbase;
  wtiles = wtiles < 0 ? 0 : (wtiles > cnt ? cnt : wtiles);

  f32x4 acc[2][16] = {};
  bf16x8 qa[2][4];
  #pragma unroll
  for (int rt = 0; rt < 2; rt++){
    const bf16* qh = Qhi + base + (size_t)(t0 + rt*16 + lc)*HD;
    const bf16* ql = Qlo + base + (size_t)(t0 + rt*16 + lc)*HD;
    qa[rt][0] = ld8(qh + quad*8); qa[rt][1] = ld8(qh + 32 + quad*8);
    qa[rt][2] = ld8(ql + quad*8); qa[rt][3] = ld8(ql + 32 + quad*8);
  }

  // QK: 2-buffer K prefetch, distance 1; 12 MFMA per K-tile load
  bf16x8 kb[2][4];
  auto loadK = [&](int tl, int b){
    const bf16* kh = Khi + base + (size_t)((wbase + tl)*16 + lc)*HD;
    const bf16* kl = Klo + base + (size_t)((wbase + tl)*16 + lc)*HD;
    kb[b][0] = ld8(kh + quad*8);  kb[b][1] = ld8(kh + 32 + quad*8);
    kb[b][2] = ld8(kl + quad*8);  kb[b][3] = ld8(kl + 32 + quad*8);
  };
  if (wtiles > 0) loadK(0, 0);
  #pragma unroll
  for (int tl = 0; tl < 16; tl++){
    if (tl < wtiles){
      if (tl + 1 < wtiles) loadK(tl + 1, (tl + 1) & 1);
      const int b = tl & 1;
      #pragma unroll
      for (int rt = 0; rt < 2; rt++){
        acc[rt][tl] = mfma16(qa[rt][0], kb[b][0], acc[rt][tl]);
        acc[rt][tl] = mfma16(qa[rt][1], kb[b][1], acc[rt][tl]);
        acc[rt][tl] = mfma16(qa[rt][0], kb[b][2], acc[rt][tl]);
        acc[rt][tl] = mfma16(qa[rt][1], kb[b][3], acc[rt][tl]);
        acc[rt][tl] = mfma16(qa[rt][2], kb[b][0], acc[rt][tl]);
        acc[rt][tl] = mfma16(qa[rt][3], kb[b][1], acc[rt][tl]);
      }
    }
  }

  float mx[2][4], sm[2][4];
  #pragma unroll
  for (int rt = 0; rt < 2; rt++)
    #pragma unroll
    for (int i = 0; i < 4; i++){ mx[rt][i] = NEGINF; sm[rt][i] = 0.f; }

  #pragma unroll
  for (int tl = 0; tl < 16; tl++){
    if (tl < wtiles){
      int col = (wbase + tl)*16 + lc;
      #pragma unroll
      for (int rt = 0; rt < 2; rt++){
        #pragma unroll
        for (int i = 0; i < 4; i++){
          int r = t0 + rt*16 + quad*4 + i;
          float v = acc[rt][tl][i];
          if (col <= r && v != 0.0f) mx[rt][i] = fmaxf(mx[rt][i], v);
        }
      }
    }
  }
  #pragma unroll
  for (int off = 8; off; off >>= 1)
    #pragma unroll
    for (int rt = 0; rt < 2; rt++)
      #pragma unroll
      for (int i = 0; i < 4; i++) mx[rt][i] = fmaxf(mx[rt][i], __shfl_xor(mx[rt][i], off, 16));

  #pragma unroll
  for (int tl = 0; tl < 16; tl++){
    if (tl < wtiles){
      int col = (wbase + tl)*16 + lc;
      #pragma unroll
      for (int rt = 0; rt < 2; rt++){
        #pragma unroll
        for (int i = 0; i < 4; i++){
          int r = t0 + rt*16 + quad*4 + i;
          float v = acc[rt][tl][i];
          float e = (col <= r && v != 0.0f) ? __expf(v - mx[rt][i]) : 0.0f;
          acc[rt][tl][i] = e;
          sm[rt][i] += e;
        }
      }
    }
  }
  #pragma unroll
  for (int off = 8; off; off >>= 1)
    #pragma unroll
    for (int rt = 0; rt < 2; rt++)
      #pragma unroll
      for (int i = 0; i < 4; i++) sm[rt][i] += __shfl_xor(sm[rt][i], off, 16);

  if (lc == 0){
    #pragma unroll
    for (int rt = 0; rt < 2; rt++)
      #pragma unroll
      for (int i = 0; i < 4; i++){
        msh[w][rt*16 + quad*4 + i] = mx[rt][i];
        lsh[w][rt*16 + quad*4 + i] = sm[rt][i];
      }
  }
  __syncthreads();
  float scale[2][4];
  #pragma unroll
  for (int rt = 0; rt < 2; rt++){
    #pragma unroll
    for (int i = 0; i < 4; i++){
      int rl = rt*16 + quad*4 + i;
      float M = fmaxf(fmaxf(msh[0][rl], msh[1][rl]), fmaxf(msh[2][rl], msh[3][rl]));
      float L = 0.f;
      #pragma unroll
      for (int w2 = 0; w2 < 4; w2++) L += lsh[w2][rl] * __expf(msh[w2][rl] - M);
      scale[rt][i] = __expf(mx[rt][i] - M) / L;
    }
  }

  // process P in two 512-col halves: stage -> attn store -> PV partial
  f32x4 o0a = {}, o0b = {}, o1a = {}, o1b = {};
  #pragma unroll
  for (int hh = 0; hh < 2; hh++){
    const int lo = hh * 512;
    if (lo < kend){
      const int hi = (kend < lo + 512) ? kend : lo + 512;
      // stage this half's tiles
      #pragma unroll
      for (int tl = 0; tl < 16; tl++){
        if (tl < wtiles && ((wbase + tl) >> 5) == hh){
          int col = (wbase + tl)*16 + lc - lo;
          #pragma unroll
          for (int rt = 0; rt < 2; rt++)
            #pragma unroll
            for (int i = 0; i < 4; i++)
              sP[rt*16 + quad*4 + i][col] = __float2bfloat16(acc[rt][tl][i] * scale[rt][i]);
        }
      }
      __syncthreads();

      // attn store, causal-cropped, nontemporal; 2 rows per iteration (all 256 threads)
      {
        const int colb = (tid & 127) * 4;
        const int rh = tid >> 7;       // 0/1
        if (colb < hi - lo){
          #pragma unroll
          for (int rp = 0; rp < 16; rp++){
            int r = rp*2 + rh;
            const unsigned* sPu = (const unsigned*)&sP[r][0];
            uint2 v = *(const uint2*)(sPu + (tid & 127)*2);
            f32x4 f;
            f[0] = __uint_as_float(v.x << 16);
            f[1] = __uint_as_float(v.x & 0xFFFF0000u);
            f[2] = __uint_as_float(v.y << 16);
            f[3] = __uint_as_float(v.y & 0xFFFF0000u);
            __builtin_nontemporal_store(f, (f32x4*)(attn + ((size_t)nh*SEQ + t0 + r)*SEQ + lo + colb));
          }
        }
      }

      // PV partial for this half: one V load feeds both row-tiles
      {
        const int nch = (hi - lo) >> 5;
        const bf16* Vb = Vt + ((size_t)nh*HD + w*16 + lc)*SEQ + lo;
        bf16x8 v0, v1;
        v0 = ld8(Vb + quad*8);
        if (nch > 1) v1 = ld8(Vb + 32 + quad*8);
        int ch = 0;
        for (; ch + 2 <= nch; ch += 2){
          const int s0 = ch*32;
          o0a = mfma16(*(const bf16x8*)&sP[lc][s0 + quad*8],      v0, o0a);
          o1a = mfma16(*(const bf16x8*)&sP[16 + lc][s0 + quad*8], v0, o1a);
          if (ch + 2 < nch) v0 = ld8(Vb + (ch+2)*32 + quad*8);
          o0b = mfma16(*(const bf16x8*)&sP[lc][s0 + 32 + quad*8],      v1, o0b);
          o1b = mfma16(*(const bf16x8*)&sP[16 + lc][s0 + 32 + quad*8], v1, o1b);
          if (ch + 3 < nch) v1 = ld8(Vb + (ch+3)*32 + quad*8);
        }
        if (ch < nch){
          const int s0 = ch*32;
          o0a = mfma16(*(const bf16x8*)&sP[lc][s0 + quad*8],      v0, o0a);
          o1a = mfma16(*(const bf16x8*)&sP[16 + lc][s0 + quad*8], v0, o1a);
        }
      }
      __syncthreads();   // protect sP before next half restage
    }
  }

  const int n = nh / NH, h = nh % NH;
  #pragma unroll
  for (int i = 0; i < 4; i++){
    O[((size_t)n*SEQ + t0 + quad*4 + i)*DM + h*HD + w*16 + lc]      = __float2bfloat16(o0a[i] + o0b[i]);
    O[((size_t)n*SEQ + t0 + 16 + quad*4 + i)*DM + h*HD + w*16 + lc] = __float2bfloat16(o1a[i] + o1b[i]);
  }
}

// ---------------- out = O @ Wo + bo  (M-tile 16, 4-deep pipelined K loop) ----------------
__global__ __launch_bounds__(256) void kout(const bf16* __restrict__ O, const bf16* __restrict__ WoT,
                                            const float* __restrict__ bo, float* __restrict__ out){
  const int lane = threadIdx.x & 63, w = threadIdx.x >> 6;
  const int quad = lane >> 4, lc = lane & 15;
  const int g = blockIdx.x * 16;
  const int n = g >> 10, tb = g & 1023;
  const bf16* Or = O + ((size_t)n*SEQ + tb + lc)*DM + quad*8;
  const bf16* Wr = WoT + (size_t)(w*16 + lc)*DM + quad*8;
  f32x4 ac0 = {}, ac1 = {};
  bf16x8 a0 = ld8(Or), b0 = ld8(Wr);
  bf16x8 a1 = ld8(Or + 32),  b1 = ld8(Wr + 32);
  bf16x8 a2 = ld8(Or + 64),  b2 = ld8(Wr + 64);
  bf16x8 a3 = ld8(Or + 96),  b3 = ld8(Wr + 96);
  #pragma unroll
  for (int gr = 0; gr < 6; gr++){
    const int k0 = gr*128;
    ac0 = mfma16(a0, b0, ac0);
    if (gr < 5){ a0 = ld8(Or + k0 + 128); b0 = ld8(Wr + k0 + 128); }
    ac1 = mfma16(a1, b1, ac1);
    if (gr < 5){ a1 = ld8(Or + k0 + 160); b1 = ld8(Wr + k0 + 160); }
    ac0 = mfma16(a2, b2, ac0);
    if (gr < 5){ a2 = ld8(Or + k0 + 192); b2 = ld8(Wr + k0 + 192); }
    ac1 = mfma16(a3, b3, ac1);
    if (gr < 5){ a3 = ld8(Or + k0 + 224); b3 = ld8(Wr + k0 + 224); }
  }
  float bias = bo[w*16 + lc];
  #pragma unroll
  for (int i = 0; i < 4; i++){
    out[((size_t)n*SEQ + tb + quad*4 + i)*HD + w*16 + lc] = ac0[i] + ac1[i] + bias;
  }
}

extern "C" void kernel_launch(void* const* d_in, const int* in_sizes, int n_in,
                              void* d_out, int out_size, void* d_ws, size_t ws_size,
                              hipStream_t stream){
  const float* x  = (const float*)d_in[0];
  const float* Wq = (const float*)d_in[1];
  const float* Wk = (const float*)d_in[2];
  const float* Wv = (const float*)d_in[3];
  const float* Wo = (const float*)d_in[4];
  const float* bo = (const float*)d_in[5];

  float* out  = (float*)d_out;
  float* attn = out + (size_t)NB*SEQ*HD;

  constexpr size_t SZ_WT  = (size_t)NH*HD*DM;
  constexpr size_t SZ_WOT = (size_t)HD*DM;
  constexpr size_t SZ_Q   = (size_t)NB*NH*SEQ*HD;
  bf16* b = (bf16*)d_ws;
  bf16* WqTh = b;  b += SZ_WT;
  bf16* WqTl = b;  b += SZ_WT;
  bf16* WkTh = b;  b += SZ_WT;
  bf16* WkTl = b;  b += SZ_WT;
  bf16* WvT  = b;  b += SZ_WT;
  bf16* WoT  = b;  b += SZ_WOT;
  bf16* xh   = b;  b += SZ_Q;
  bf16* xl   = b;  b += SZ_Q;
  bf16* Qhi  = b;  b += SZ_Q;
  bf16* Qlo  = b;  b += SZ_Q;
  bf16* Khi  = b;  b += SZ_Q;
  bf16* Klo  = b;  b += SZ_Q;
  bf16* Vt   = b;  b += SZ_Q;
  bf16* O    = xh;   // alias: xh dead after kproj

  wprep<<<dim3(12, 37), 256, 0, stream>>>(Wq, Wk, Wv, Wo, WqTh, WqTl, WkTh, WkTl, WvT, WoT);
  xprep<<<dim3((int)(SZ_Q/(256*8))), 256, 0, stream>>>(x, xh, xl);
  kproj<<<dim3(NB*SEQ/128, NH), 256, 0, stream>>>(xh, xl, WqTh, WqTl, WkTh, WkTl, WvT,
                                                  Qhi, Qlo, Khi, Klo, Vt);
  kattn_pv<<<dim3(NB*NH*SEQ/32), 256, 0, stream>>>(Qhi, Qlo, Khi, Klo, Vt, attn, O);
  kout<<<dim3(NB*SEQ/16), 256, 0, stream>>>(O, WoT, bo, out);
}

// Round 9
// 308.531 us; speedup vs baseline: 1.0349x; 1.0349x over previous
//
#include <hip/hip_runtime.h>
#include <hip/hip_bf16.h>

typedef __hip_bfloat16 bf16;
typedef __attribute__((ext_vector_type(8))) short bf16x8;
typedef __attribute__((ext_vector_type(4))) float f32x4;

constexpr int NB  = 4;
constexpr int NH  = 12;
constexpr int SEQ = 1024;
constexpr int HD  = 64;
constexpr int DM  = 768;
constexpr int LDA = 40;   // padded LDS row (elems)

__device__ __forceinline__ bf16x8 ld8(const bf16* p){ return *(const bf16x8*)p; }
__device__ __forceinline__ f32x4 mfma16(bf16x8 a, bf16x8 b, f32x4 c){
  return __builtin_amdgcn_mfma_f32_16x16x32_bf16(a, b, c, 0, 0, 0);
}
union U8 { bf16x8 v; bf16 h[8]; };

// ---------------- wprep: LDS-tiled transpose, fp32 W[.][d][e] -> bf16 WT[.][e][d] ----------------
__global__ __launch_bounds__(256) void wprep(const float* __restrict__ Wq, const float* __restrict__ Wk,
                      const float* __restrict__ Wv, const float* __restrict__ Wo,
                      bf16* __restrict__ WqTh, bf16* __restrict__ WqTl,
                      bf16* __restrict__ WkTh, bf16* __restrict__ WkTl,
                      bf16* __restrict__ WvT,  bf16* __restrict__ WoT){
  __shared__ float sT[64][65];
  const int tid = threadIdx.x;
  const int dt = blockIdx.x, y = blockIdx.y;
  const float* src; bf16* dh; bf16* dl = nullptr;
  if (y < 36){
    int z = y / 12, h = y % 12;
    src = (z==0 ? Wq : z==1 ? Wk : Wv) + (size_t)h*DM*HD;
    dh  = (z==0 ? WqTh : z==1 ? WkTh : WvT) + (size_t)h*HD*DM;
    if (z==0) dl = WqTl + (size_t)h*HD*DM;
    if (z==1) dl = WkTl + (size_t)h*HD*DM;
  } else { src = Wo; dh = WoT; }

  {
    int r = tid >> 2, c = (tid & 3) * 16;
    const float* sp = src + ((size_t)(dt*64 + r))*HD + c;
    f32x4 v0 = *(const f32x4*)sp, v1 = *(const f32x4*)(sp+4),
          v2 = *(const f32x4*)(sp+8), v3 = *(const f32x4*)(sp+12);
    #pragma unroll
    for (int j = 0; j < 4; j++){
      sT[r][c+j] = v0[j]; sT[r][c+4+j] = v1[j]; sT[r][c+8+j] = v2[j]; sT[r][c+12+j] = v3[j];
    }
  }
  __syncthreads();
  {
    int e = tid >> 2, co = (tid & 3) * 16;
    U8 uh0, ul0, uh1, ul1;
    #pragma unroll
    for (int j = 0; j < 8; j++){
      float v = sT[co + j][e];
      bf16 hi = __float2bfloat16(v);
      uh0.h[j] = hi; ul0.h[j] = __float2bfloat16(v - __bfloat162float(hi));
    }
    #pragma unroll
    for (int j = 0; j < 8; j++){
      float v = sT[co + 8 + j][e];
      bf16 hi = __float2bfloat16(v);
      uh1.h[j] = hi; ul1.h[j] = __float2bfloat16(v - __bfloat162float(hi));
    }
    size_t o = (size_t)e*DM + dt*64 + co;
    *(bf16x8*)(dh + o) = uh0.v; *(bf16x8*)(dh + o + 8) = uh1.v;
    if (dl){ *(bf16x8*)(dl + o) = ul0.v; *(bf16x8*)(dl + o + 8) = ul1.v; }
  }
}

// ---------------- xprep ----------------
__global__ __launch_bounds__(256) void xprep(const float* __restrict__ x,
                                             bf16* __restrict__ xh, bf16* __restrict__ xl){
  size_t base = ((size_t)blockIdx.x*256 + threadIdx.x)*8;
  f32x4 a = *(const f32x4*)(x + base), b = *(const f32x4*)(x + base + 4);
  U8 uh, ul;
  #pragma unroll
  for (int j = 0; j < 4; j++){
    bf16 h0 = __float2bfloat16(a[j]);
    uh.h[j] = h0; ul.h[j] = __float2bfloat16(a[j] - __bfloat162float(h0));
    bf16 h1 = __float2bfloat16(b[j]);
    uh.h[4+j] = h1; ul.h[4+j] = __float2bfloat16(b[j] - __bfloat162float(h1));
  }
  *(bf16x8*)(xh + base) = uh.v;
  *(bf16x8*)(xl + base) = ul.v;
}

// ---------------- kproj: LDS-staged GEMM (R7 two-pass version) ----------------
// z=0: Q AND K (share staged x tiles, hi/lo 3-term)  out [nh][t][e] hi+lo
// z=1: V (A=WvT 64 e-rows, B=xh 128 t-cols)          out Vt [nh][e][t]
__global__ __launch_bounds__(256) void kproj(const bf16* __restrict__ xh, const bf16* __restrict__ xl,
    const bf16* __restrict__ WqTh, const bf16* __restrict__ WqTl,
    const bf16* __restrict__ WkTh, const bf16* __restrict__ WkTl,
    const bf16* __restrict__ WvT,
    bf16* __restrict__ Qhi, bf16* __restrict__ Qlo,
    bf16* __restrict__ Khi, bf16* __restrict__ Klo, bf16* __restrict__ Vt){
  __shared__ bf16 sA[2][128*LDA];
  __shared__ bf16 sB[4][64*LDA];
  const int tid = threadIdx.x;
  const int lane = tid & 63, w = tid >> 6;
  const int quad = lane >> 4, lc = lane & 15;
  const int mb = blockIdx.x, h = blockIdx.y, z = blockIdx.z;
  const int sr = tid >> 2;
  const int sc = (tid & 3) * 8;
  const int wm = w & 1, wn = w >> 1;

  if (z == 0){
    const bf16* Bqh = WqTh + (size_t)h*HD*DM;
    const bf16* Bql = WqTl + (size_t)h*HD*DM;
    const bf16* Bkh = WkTh + (size_t)h*HD*DM;
    const bf16* Bkl = WkTl + (size_t)h*HD*DM;
    f32x4 aq[4][2] = {}, ak[4][2] = {};
    bf16x8 pa0,pa1,pa2,pa3,pq0,pq1,pk0,pk1;
    auto ldchunk = [&](int kc){
      size_t col = (size_t)kc*32 + sc;
      pa0 = ld8(xh + (size_t)(mb*128 + sr)*DM + col);
      pa1 = ld8(xh + (size_t)(mb*128 + sr + 64)*DM + col);
      pa2 = ld8(xl + (size_t)(mb*128 + sr)*DM + col);
      pa3 = ld8(xl + (size_t)(mb*128 + sr + 64)*DM + col);
      pq0 = ld8(Bqh + (size_t)sr*DM + col);
      pq1 = ld8(Bql + (size_t)sr*DM + col);
      pk0 = ld8(Bkh + (size_t)sr*DM + col);
      pk1 = ld8(Bkl + (size_t)sr*DM + col);
    };
    ldchunk(0);
    for (int kc = 0; kc < DM/32; kc++){
      *(bf16x8*)&sA[0][sr*LDA + sc] = pa0;
      *(bf16x8*)&sA[0][(sr+64)*LDA + sc] = pa1;
      *(bf16x8*)&sA[1][sr*LDA + sc] = pa2;
      *(bf16x8*)&sA[1][(sr+64)*LDA + sc] = pa3;
      *(bf16x8*)&sB[0][sr*LDA + sc] = pq0;
      *(bf16x8*)&sB[1][sr*LDA + sc] = pq1;
      *(bf16x8*)&sB[2][sr*LDA + sc] = pk0;
      *(bf16x8*)&sB[3][sr*LDA + sc] = pk1;
      __syncthreads();
      if (kc < DM/32 - 1) ldchunk(kc + 1);
      bf16x8 bqh[2], bql[2], bkh[2], bkl[2];
      #pragma unroll
      for (int nt = 0; nt < 2; nt++){
        int ro = (wn*32 + nt*16 + lc)*LDA + quad*8;
        bqh[nt] = *(const bf16x8*)&sB[0][ro];
        bql[nt] = *(const bf16x8*)&sB[1][ro];
        bkh[nt] = *(const bf16x8*)&sB[2][ro];
        bkl[nt] = *(const bf16x8*)&sB[3][ro];
      }
      #pragma unroll
      for (int mt = 0; mt < 4; mt++){
        bf16x8 ah = *(const bf16x8*)&sA[0][(wm*64 + mt*16 + lc)*LDA + quad*8];
        bf16x8 al = *(const bf16x8*)&sA[1][(wm*64 + mt*16 + lc)*LDA + quad*8];
        #pragma unroll
        for (int nt = 0; nt < 2; nt++){
          aq[mt][nt] = mfma16(ah, bqh[nt], aq[mt][nt]);
          aq[mt][nt] = mfma16(ah, bql[nt], aq[mt][nt]);
          aq[mt][nt] = mfma16(al, bqh[nt], aq[mt][nt]);
          ak[mt][nt] = mfma16(ah, bkh[nt], ak[mt][nt]);
          ak[mt][nt] = mfma16(ah, bkl[nt], ak[mt][nt]);
          ak[mt][nt] = mfma16(al, bkh[nt], ak[mt][nt]);
        }
      }
      __syncthreads();
    }
    #pragma unroll
    for (int mt = 0; mt < 4; mt++){
      #pragma unroll
      for (int nt = 0; nt < 2; nt++){
        #pragma unroll
        for (int i = 0; i < 4; i++){
          int tg = mb*128 + wm*64 + mt*16 + quad*4 + i;
          int e  = wn*32 + nt*16 + lc;
          int n = tg >> 10, t = tg & 1023;
          size_t o = ((size_t)(n*NH + h)*SEQ + t)*HD + e;
          float vq = aq[mt][nt][i];
          bf16 hq = __float2bfloat16(vq);
          Qhi[o] = hq;
          Qlo[o] = __float2bfloat16(vq - __bfloat162float(hq));
          float vk = ak[mt][nt][i];
          bf16 hk = __float2bfloat16(vk);
          Khi[o] = hk;
          Klo[o] = __float2bfloat16(vk - __bfloat162float(hk));
        }
      }
    }
  } else {
    const bf16* Av = WvT + (size_t)h*HD*DM;
    f32x4 acc[2][4] = {};
    bf16x8 pa0, pb0, pb1;
    auto ldchunk = [&](int kc){
      size_t col = (size_t)kc*32 + sc;
      pa0 = ld8(Av + (size_t)sr*DM + col);
      pb0 = ld8(xh + (size_t)(mb*128 + sr)*DM + col);
      pb1 = ld8(xh + (size_t)(mb*128 + sr + 64)*DM + col);
    };
    ldchunk(0);
    for (int kc = 0; kc < DM/32; kc++){
      *(bf16x8*)&sB[0][sr*LDA + sc] = pa0;
      *(bf16x8*)&sA[0][sr*LDA + sc] = pb0;
      *(bf16x8*)&sA[0][(sr+64)*LDA + sc] = pb1;
      __syncthreads();
      if (kc < DM/32 - 1) ldchunk(kc + 1);
      bf16x8 bt[4];
      #pragma unroll
      for (int nt = 0; nt < 4; nt++)
        bt[nt] = *(const bf16x8*)&sA[0][(wn*64 + nt*16 + lc)*LDA + quad*8];
      #pragma unroll
      for (int mt = 0; mt < 2; mt++){
        bf16x8 a = *(const bf16x8*)&sB[0][(wm*32 + mt*16 + lc)*LDA + quad*8];
        #pragma unroll
        for (int nt = 0; nt < 4; nt++)
          acc[mt][nt] = mfma16(a, bt[nt], acc[mt][nt]);
      }
      __syncthreads();
    }
    #pragma unroll
    for (int mt = 0; mt < 2; mt++){
      #pragma unroll
      for (int nt = 0; nt < 4; nt++){
        #pragma unroll
        for (int i = 0; i < 4; i++){
          int e  = wm*32 + mt*16 + quad*4 + i;
          int tg = mb*128 + wn*64 + nt*16 + lc;
          int n = tg >> 10, t = tg & 1023;
          Vt[((size_t)(n*NH + h)*HD + e)*SEQ + t] = __float2bfloat16(acc[mt][nt][i]);
        }
      }
    }
  }
}

// ---------------- fused scores + softmax + attn-stream + PV ----------------
// 32 Q-rows per block; FULL-WIDTH sP (single stage + single barrier pair).
// V loads issued before the staging barrier to hide latency under stage+store.
// Grid 1536 = 8 XCD x 6 heads x 32 tt-pairs, LPT descending.
__global__ __launch_bounds__(256, 2) void kattn_pv(const bf16* __restrict__ Qhi, const bf16* __restrict__ Qlo,
                                                   const bf16* __restrict__ Khi, const bf16* __restrict__ Klo,
                                                   const bf16* __restrict__ Vt,
                                                   float* __restrict__ attn, bf16* __restrict__ O){
  __shared__ bf16 sP[32][1040];
  __shared__ float msh[4][32], lsh[4][32];
  const int tid = threadIdx.x;
  const int lane = tid & 63, w = tid >> 6;
  const int quad = lane >> 4, lc = lane & 15;
  const int lin = blockIdx.x;          // 0..1535
  const int xcd = lin & 7;
  const int c   = lin >> 3;            // 0..191
  const int nh  = xcd * 6 + (c >> 5);  // 48 heads / 8 XCDs
  const int tp  = 31 - (c & 31);       // tt-pair, DESCENDING -> LPT
  const int t0  = tp * 32;
  const size_t base = (size_t)nh * SEQ * HD;
  const float NEGINF = -__builtin_inff();

  const int kend = t0 + 32;            // multiple of 32 -> no PV tail fill
  const int T_act = 2*tp + 2;          // active 16-wide col-tiles
  const int cnt   = (T_act + 3) >> 2;
  const int wbase = w * cnt;
  int wtiles = T_act - wbase;
  wtiles = wtiles < 0 ? 0 : (wtiles > cnt ? cnt : wtiles);

  f32x4 acc[2][16] = {};
  bf16x8 qa[2][4];
  #pragma unroll
  for (int rt = 0; rt < 2; rt++){
    const bf16* qh = Qhi + base + (size_t)(t0 + rt*16 + lc)*HD;
    const bf16* ql = Qlo + base + (size_t)(t0 + rt*16 + lc)*HD;
    qa[rt][0] = ld8(qh + quad*8); qa[rt][1] = ld8(qh + 32 + quad*8);
    qa[rt][2] = ld8(ql + quad*8); qa[rt][3] = ld8(ql + 32 + quad*8);
  }

  // QK: 2-buffer K prefetch, distance 1; 12 MFMA per K-tile load
  bf16x8 kb[2][4];
  auto loadK = [&](int tl, int b){
    const bf16* kh = Khi + base + (size_t)((wbase + tl)*16 + lc)*HD;
    const bf16* kl = Klo + base + (size_t)((wbase + tl)*16 + lc)*HD;
    kb[b][0] = ld8(kh + quad*8);  kb[b][1] = ld8(kh + 32 + quad*8);
    kb[b][2] = ld8(kl + quad*8);  kb[b][3] = ld8(kl + 32 + quad*8);
  };
  if (wtiles > 0) loadK(0, 0);
  #pragma unroll
  for (int tl = 0; tl < 16; tl++){
    if (tl < wtiles){
      if (tl + 1 < wtiles) loadK(tl + 1, (tl + 1) & 1);
      const int b = tl & 1;
      #pragma unroll
      for (int rt = 0; rt < 2; rt++){
        acc[rt][tl] = mfma16(qa[rt][0], kb[b][0], acc[rt][tl]);
        acc[rt][tl] = mfma16(qa[rt][1], kb[b][1], acc[rt][tl]);
        acc[rt][tl] = mfma16(qa[rt][0], kb[b][2], acc[rt][tl]);
        acc[rt][tl] = mfma16(qa[rt][1], kb[b][3], acc[rt][tl]);
        acc[rt][tl] = mfma16(qa[rt][2], kb[b][0], acc[rt][tl]);
        acc[rt][tl] = mfma16(qa[rt][3], kb[b][1], acc[rt][tl]);
      }
    }
  }

  float mx[2][4], sm[2][4];
  #pragma unroll
  for (int rt = 0; rt < 2; rt++)
    #pragma unroll
    for (int i = 0; i < 4; i++){ mx[rt][i] = NEGINF; sm[rt][i] = 0.f; }

  #pragma unroll
  for (int tl = 0; tl < 16; tl++){
    if (tl < wtiles){
      int col = (wbase + tl)*16 + lc;
      #pragma unroll
      for (int rt = 0; rt < 2; rt++){
        #pragma unroll
        for (int i = 0; i < 4; i++){
          int r = t0 + rt*16 + quad*4 + i;
          float v = acc[rt][tl][i];
          if (col <= r && v != 0.0f) mx[rt][i] = fmaxf(mx[rt][i], v);
        }
      }
    }
  }
  #pragma unroll
  for (int off = 8; off; off >>= 1)
    #pragma unroll
    for (int rt = 0; rt < 2; rt++)
      #pragma unroll
      for (int i = 0; i < 4; i++) mx[rt][i] = fmaxf(mx[rt][i], __shfl_xor(mx[rt][i], off, 16));

  #pragma unroll
  for (int tl = 0; tl < 16; tl++){
    if (tl < wtiles){
      int col = (wbase + tl)*16 + lc;
      #pragma unroll
      for (int rt = 0; rt < 2; rt++){
        #pragma unroll
        for (int i = 0; i < 4; i++){
          int r = t0 + rt*16 + quad*4 + i;
          float v = acc[rt][tl][i];
          float e = (col <= r && v != 0.0f) ? __expf(v - mx[rt][i]) : 0.0f;
          acc[rt][tl][i] = e;
          sm[rt][i] += e;
        }
      }
    }
  }
  #pragma unroll
  for (int off = 8; off; off >>= 1)
    #pragma unroll
    for (int rt = 0; rt < 2; rt++)
      #pragma unroll
      for (int i = 0; i < 4; i++) sm[rt][i] += __shfl_xor(sm[rt][i], off, 16);

  if (lc == 0){
    #pragma unroll
    for (int rt = 0; rt < 2; rt++)
      #pragma unroll
      for (int i = 0; i < 4; i++){
        msh[w][rt*16 + quad*4 + i] = mx[rt][i];
        lsh[w][rt*16 + quad*4 + i] = sm[rt][i];
      }
  }
  __syncthreads();
  float scale[2][4];
  #pragma unroll
  for (int rt = 0; rt < 2; rt++){
    #pragma unroll
    for (int i = 0; i < 4; i++){
      int rl = rt*16 + quad*4 + i;
      float M = fmaxf(fmaxf(msh[0][rl], msh[1][rl]), fmaxf(msh[2][rl], msh[3][rl]));
      float L = 0.f;
      #pragma unroll
      for (int w2 = 0; w2 < 4; w2++) L += lsh[w2][rl] * __expf(msh[w2][rl] - M);
      scale[rt][i] = __expf(mx[rt][i] - M) / L;
    }
  }

  // issue first V loads NOW (independent of sP) — latency hides under stage+store
  const bf16* Vb = Vt + ((size_t)nh*HD + w*16 + lc)*SEQ;
  const int nch = kend >> 5;           // 1..32
  bf16x8 v0, v1;
  v0 = ld8(Vb + quad*8);
  if (nch > 1) v1 = ld8(Vb + 32 + quad*8);

  // stage ALL active tiles (full-width sP, single pass)
  #pragma unroll
  for (int tl = 0; tl < 16; tl++){
    if (tl < wtiles){
      int col = (wbase + tl)*16 + lc;
      #pragma unroll
      for (int rt = 0; rt < 2; rt++)
        #pragma unroll
        for (int i = 0; i < 4; i++)
          sP[rt*16 + quad*4 + i][col] = __float2bfloat16(acc[rt][tl][i] * scale[rt][i]);
    }
  }
  __syncthreads();

  // attn store, causal-cropped, nontemporal: 256 threads cover one full 1024-col row/iter
  {
    const int colb = tid * 4;
    if (colb < kend){
      #pragma unroll
      for (int r = 0; r < 32; r++){
        const unsigned* sPu = (const unsigned*)&sP[r][0];
        uint2 v = *(const uint2*)(sPu + tid*2);
        f32x4 f;
        f[0] = __uint_as_float(v.x << 16);
        f[1] = __uint_as_float(v.x & 0xFFFF0000u);
        f[2] = __uint_as_float(v.y << 16);
        f[3] = __uint_as_float(v.y & 0xFFFF0000u);
        __builtin_nontemporal_store(f, (f32x4*)(attn + ((size_t)nh*SEQ + t0 + r)*SEQ + colb));
      }
    }
  }

  // PV: full column sweep, 2-deep V prefetch, one V load feeds both row-tiles
  f32x4 o0a = {}, o0b = {}, o1a = {}, o1b = {};
  int ch = 0;
  for (; ch + 2 <= nch; ch += 2){
    const int s0 = ch*32;
    o0a = mfma16(*(const bf16x8*)&sP[lc][s0 + quad*8],      v0, o0a);
    o1a = mfma16(*(const bf16x8*)&sP[16 + lc][s0 + quad*8], v0, o1a);
    if (ch + 2 < nch) v0 = ld8(Vb + (ch+2)*32 + quad*8);
    o0b = mfma16(*(const bf16x8*)&sP[lc][s0 + 32 + quad*8],      v1, o0b);
    o1b = mfma16(*(const bf16x8*)&sP[16 + lc][s0 + 32 + quad*8], v1, o1b);
    if (ch + 3 < nch) v1 = ld8(Vb + (ch+3)*32 + quad*8);
  }
  if (ch < nch){
    const int s0 = ch*32;
    o0a = mfma16(*(const bf16x8*)&sP[lc][s0 + quad*8],      v0, o0a);
    o1a = mfma16(*(const bf16x8*)&sP[16 + lc][s0 + quad*8], v0, o1a);
  }

  const int n = nh / NH, h = nh % NH;
  #pragma unroll
  for (int i = 0; i < 4; i++){
    O[((size_t)n*SEQ + t0 + quad*4 + i)*DM + h*HD + w*16 + lc]      = __float2bfloat16(o0a[i] + o0b[i]);
    O[((size_t)n*SEQ + t0 + 16 + quad*4 + i)*DM + h*HD + w*16 + lc] = __float2bfloat16(o1a[i] + o1b[i]);
  }
}

// ---------------- out = O @ Wo + bo  (M-tile 16, 4-deep pipelined K loop) ----------------
__global__ __launch_bounds__(256) void kout(const bf16* __restrict__ O, const bf16* __restrict__ WoT,
                                            const float* __restrict__ bo, float* __restrict__ out){
  const int lane = threadIdx.x & 63, w = threadIdx.x >> 6;
  const int quad = lane >> 4, lc = lane & 15;
  const int g = blockIdx.x * 16;
  const int n = g >> 10, tb = g & 1023;
  const bf16* Or = O + ((size_t)n*SEQ + tb + lc)*DM + quad*8;
  const bf16* Wr = WoT + (size_t)(w*16 + lc)*DM + quad*8;
  f32x4 ac0 = {}, ac1 = {};
  bf16x8 a0 = ld8(Or), b0 = ld8(Wr);
  bf16x8 a1 = ld8(Or + 32),  b1 = ld8(Wr + 32);
  bf16x8 a2 = ld8(Or + 64),  b2 = ld8(Wr + 64);
  bf16x8 a3 = ld8(Or + 96),  b3 = ld8(Wr + 96);
  #pragma unroll
  for (int gr = 0; gr < 6; gr++){
    const int k0 = gr*128;
    ac0 = mfma16(a0, b0, ac0);
    if (gr < 5){ a0 = ld8(Or + k0 + 128); b0 = ld8(Wr + k0 + 128); }
    ac1 = mfma16(a1, b1, ac1);
    if (gr < 5){ a1 = ld8(Or + k0 + 160); b1 = ld8(Wr + k0 + 160); }
    ac0 = mfma16(a2, b2, ac0);
    if (gr < 5){ a2 = ld8(Or + k0 + 192); b2 = ld8(Wr + k0 + 192); }
    ac1 = mfma16(a3, b3, ac1);
    if (gr < 5){ a3 = ld8(Or + k0 + 224); b3 = ld8(Wr + k0 + 224); }
  }
  float bias = bo[w*16 + lc];
  #pragma unroll
  for (int i = 0; i < 4; i++){
    out[((size_t)n*SEQ + tb + quad*4 + i)*HD + w*16 + lc] = ac0[i] + ac1[i] + bias;
  }
}

extern "C" void kernel_launch(void* const* d_in, const int* in_sizes, int n_in,
                              void* d_out, int out_size, void* d_ws, size_t ws_size,
                              hipStream_t stream){
  const float* x  = (const float*)d_in[0];
  const float* Wq = (const float*)d_in[1];
  const float* Wk = (const float*)d_in[2];
  const float* Wv = (const float*)d_in[3];
  const float* Wo = (const float*)d_in[4];
  const float* bo = (const float*)d_in[5];

  float* out  = (float*)d_out;
  float* attn = out + (size_t)NB*SEQ*HD;

  constexpr size_t SZ_WT  = (size_t)NH*HD*DM;
  constexpr size_t SZ_WOT = (size_t)HD*DM;
  constexpr size_t SZ_Q   = (size_t)NB*NH*SEQ*HD;
  bf16* b = (bf16*)d_ws;
  bf16* WqTh = b;  b += SZ_WT;
  bf16* WqTl = b;  b += SZ_WT;
  bf16* WkTh = b;  b += SZ_WT;
  bf16* WkTl = b;  b += SZ_WT;
  bf16* WvT  = b;  b += SZ_WT;
  bf16* WoT  = b;  b += SZ_WOT;
  bf16* xh   = b;  b += SZ_Q;
  bf16* xl   = b;  b += SZ_Q;
  bf16* Qhi  = b;  b += SZ_Q;
  bf16* Qlo  = b;  b += SZ_Q;
  bf16* Khi  = b;  b += SZ_Q;
  bf16* Klo  = b;  b += SZ_Q;
  bf16* Vt   = b;  b += SZ_Q;
  bf16* O    = xh;   // alias: xh dead after kproj

  wprep<<<dim3(12, 37), 256, 0, stream>>>(Wq, Wk, Wv, Wo, WqTh, WqTl, WkTh, WkTl, WvT, WoT);
  xprep<<<dim3((int)(SZ_Q/(256*8))), 256, 0, stream>>>(x, xh, xl);
  kproj<<<dim3(NB*SEQ/128, NH, 2), 256, 0, stream>>>(xh, xl, WqTh, WqTl, WkTh, WkTl, WvT,
                                                     Qhi, Qlo, Khi, Klo, Vt);
  kattn_pv<<<dim3(NB*NH*SEQ/32), 256, 0, stream>>>(Qhi, Qlo, Khi, Klo, Vt, attn, O);
  kout<<<dim3(NB*SEQ/16), 256, 0, stream>>>(O, WoT, bo, out);
}